// Round 5
// baseline (406.397 us; speedup 1.0000x reference)
//
#include <hip/hip_runtime.h>
#include <hip/hip_bf16.h>
#include <cstdint>
#include <cstddef>

#define BB 2
#define SS 2048
#define DD 2048
#define HH 16
#define HDIM 128
// 1/sqrt(128) * log2(e): folded into Q so softmax uses exp2 directly
#define QSCALE 0.12751743f

typedef short bf16x8 __attribute__((ext_vector_type(8)));
typedef float f32x4 __attribute__((ext_vector_type(4)));
typedef float f32x16 __attribute__((ext_vector_type(16)));

__device__ __forceinline__ ushort f2bf(float f) {
    union { float f; uint32_t u; } v; v.f = f;
    uint32_t u = v.u;
    u += 0x7fffu + ((u >> 16) & 1u);
    return (ushort)(u >> 16);
}

// cheap round-half-up f32->bf16 (2 VALU ops); fine for nonnegative p
__device__ __forceinline__ ushort f2bf_fast(float f) {
    union { float f; uint32_t u; } v; v.f = f;
    return (ushort)((v.u + 0x8000u) >> 16);
}

// async 16B global -> LDS (wave-uniform LDS base + lane*16)
__device__ __forceinline__ void gl16(const ushort* g, ushort* l) {
    __builtin_amdgcn_global_load_lds(
        (const __attribute__((address_space(1))) unsigned int*)g,
        (__attribute__((address_space(3))) unsigned int*)l,
        16, 0, 0);
}

// ---------------------------------------------------------------------------
// Prep kernels
// ---------------------------------------------------------------------------
__global__ __launch_bounds__(256) void cast_x_kernel(
    const float* __restrict__ X, ushort* __restrict__ Xb)
{
    size_t idx = ((size_t)blockIdx.x * 256 + threadIdx.x) * 8;
    float4 a = *(const float4*)(X + idx);
    float4 b = *(const float4*)(X + idx + 4);
    ushort4 o0, o1;
    o0.x = f2bf(a.x); o0.y = f2bf(a.y); o0.z = f2bf(a.z); o0.w = f2bf(a.w);
    o1.x = f2bf(b.x); o1.y = f2bf(b.y); o1.z = f2bf(b.z); o1.w = f2bf(b.w);
    *(ushort4*)(Xb + idx) = o0;
    *(ushort4*)(Xb + idx + 4) = o1;
}

// W fp32 [K][N] row-major -> Wt bf16 [N][K]
__global__ __launch_bounds__(256) void transpose_cast_kernel(
    const float* __restrict__ W, ushort* __restrict__ Wt, int K, int N)
{
    __shared__ ushort tile[32][36];
    const int n0 = blockIdx.x * 32;
    const int k0 = blockIdx.y * 32;
    const int t = threadIdx.x;
    const int r = t >> 3;
    const int c = (t & 7) * 4;
    float4 a = *(const float4*)(W + (size_t)(k0 + r) * N + n0 + c);
    tile[r][c + 0] = f2bf(a.x); tile[r][c + 1] = f2bf(a.y);
    tile[r][c + 2] = f2bf(a.z); tile[r][c + 3] = f2bf(a.w);
    __syncthreads();
    ushort4 o;
    o.x = tile[c + 0][r]; o.y = tile[c + 1][r];
    o.z = tile[c + 2][r]; o.w = tile[c + 3][r];
    *(ushort4*)(Wt + (size_t)(n0 + r) * K + k0 + c) = o;
}

// V bf16 [BH][S][HD] -> Vt bf16 [BH][HD][S]
__global__ __launch_bounds__(256) void transpose_v_kernel(
    const ushort* __restrict__ V, ushort* __restrict__ Vt)
{
    __shared__ ushort tile[32][36];
    const int s0 = blockIdx.x * 32;
    const int h0 = blockIdx.y * 32;
    const int bh = blockIdx.z;
    const ushort* Vp = V + (size_t)bh * SS * HDIM;
    ushort* Vtp = Vt + (size_t)bh * HDIM * SS;
    const int t = threadIdx.x;
    const int r = t >> 3;
    const int c = (t & 7) * 4;
    *(ushort4*)&tile[r][c] = *(const ushort4*)(Vp + (size_t)(s0 + r) * HDIM + h0 + c);
    __syncthreads();
    ushort4 o;
    o.x = tile[c + 0][r]; o.y = tile[c + 1][r];
    o.z = tile[c + 2][r]; o.w = tile[c + 3][r];
    *(ushort4*)(Vtp + (size_t)(h0 + r) * SS + s0 + c) = o;
}

// ---------------------------------------------------------------------------
// MFMA GEMM: C[M,N] = A[M,K] @ Bt[N,K]^T, 128x128 tile, BK=32, m97 staging.
// Inner: 32x32x16 MFMA, each wave 2x2 tiles of 32x32. Swizzled LDS chunks.
// ---------------------------------------------------------------------------
__global__ __launch_bounds__(256) void gemm_qkv_kernel(
    const ushort* __restrict__ A, const ushort* __restrict__ Bt,
    const float* __restrict__ bias,
    ushort* __restrict__ Qo, ushort* __restrict__ Ko, ushort* __restrict__ Vo)
{
    const int n0 = blockIdx.x * 128;
    const int m0 = blockIdx.y * 128;
    __shared__ ushort As[128 * 32];
    __shared__ ushort Bs[128 * 32];
    const int t = threadIdx.x, w = t >> 6, lane = t & 63;
    const int l31 = lane & 31, hh = lane >> 5;
    const int lrow = lane >> 2, lks = lane & 3;
    const int wr = w >> 1, wc = w & 1;
    const int swst = (lrow >> 1) & 3;     // store-side swizzle key
    const int swr  = (l31 >> 1) & 3;      // read-side swizzle key

    f32x16 acc[2][2];
#pragma unroll
    for (int i = 0; i < 2; ++i)
#pragma unroll
        for (int j = 0; j < 2; ++j) acc[i][j] = (f32x16)0.f;

    for (int k0 = 0; k0 < DD; k0 += 32) {
        __syncthreads();
#pragma unroll
        for (int q = 0; q < 2; ++q) {
            int e = w * 2 + q;
            int row = e * 16 + lrow;
            gl16(A  + (size_t)(m0 + row) * DD + k0 + (lks ^ swst) * 8, &As[e * 512]);
            gl16(Bt + (size_t)(n0 + row) * DD + k0 + (lks ^ swst) * 8, &Bs[e * 512]);
        }
        __syncthreads();
#pragma unroll
        for (int k16 = 0; k16 < 2; ++k16) {
            int co = ((k16 * 2 + hh) ^ swr) * 8;
            bf16x8 ar0 = *(const bf16x8*)&As[(wr * 64 + l31) * 32 + co];
            bf16x8 ar1 = *(const bf16x8*)&As[(wr * 64 + 32 + l31) * 32 + co];
            bf16x8 br0 = *(const bf16x8*)&Bs[(wc * 64 + l31) * 32 + co];
            bf16x8 br1 = *(const bf16x8*)&Bs[(wc * 64 + 32 + l31) * 32 + co];
            acc[0][0] = __builtin_amdgcn_mfma_f32_32x32x16_bf16(ar0, br0, acc[0][0], 0, 0, 0);
            acc[0][1] = __builtin_amdgcn_mfma_f32_32x32x16_bf16(ar0, br1, acc[0][1], 0, 0, 0);
            acc[1][0] = __builtin_amdgcn_mfma_f32_32x32x16_bf16(ar1, br0, acc[1][0], 0, 0, 0);
            acc[1][1] = __builtin_amdgcn_mfma_f32_32x32x16_bf16(ar1, br1, acc[1][1], 0, 0, 0);
        }
    }

    // Epilogue: bias, fold QSCALE into Q, scatter bf16 into [B,H,S,HD]
    const int bidx = m0 >> 11;
    const int which = n0 >> 11;           // block-uniform (n0 % 128 == 0)
    ushort* dst = (which == 0) ? Qo : ((which == 1) ? Ko : Vo);
    const float sc = (which == 0) ? QSCALE : 1.0f;
#pragma unroll
    for (int j = 0; j < 2; ++j) {
        int n = n0 + wc * 64 + j * 32 + l31;
        int c = n & 2047, h = c >> 7, hd = c & 127;
        float bv = bias[n];
        size_t base = ((size_t)(bidx * HH + h) * SS) * HDIM + hd;
#pragma unroll
        for (int i = 0; i < 2; ++i) {
#pragma unroll
            for (int r = 0; r < 16; ++r) {
                int s = (m0 & 2047) + wr * 64 + i * 32 + (r & 3) + 8 * (r >> 2) + 4 * hh;
                dst[base + (size_t)s * HDIM] = f2bf((acc[i][j][r] + bv) * sc);
            }
        }
    }
}

__global__ __launch_bounds__(256) void gemm_out_kernel(
    const ushort* __restrict__ A, const ushort* __restrict__ Bt,
    const float* __restrict__ bias, float* __restrict__ Out)
{
    const int n0 = blockIdx.x * 128;
    const int m0 = blockIdx.y * 128;
    __shared__ ushort As[128 * 32];
    __shared__ ushort Bs[128 * 32];
    const int t = threadIdx.x, w = t >> 6, lane = t & 63;
    const int l31 = lane & 31, hh = lane >> 5;
    const int lrow = lane >> 2, lks = lane & 3;
    const int wr = w >> 1, wc = w & 1;
    const int swst = (lrow >> 1) & 3;
    const int swr  = (l31 >> 1) & 3;

    f32x16 acc[2][2];
#pragma unroll
    for (int i = 0; i < 2; ++i)
#pragma unroll
        for (int j = 0; j < 2; ++j) acc[i][j] = (f32x16)0.f;

    for (int k0 = 0; k0 < DD; k0 += 32) {
        __syncthreads();
#pragma unroll
        for (int q = 0; q < 2; ++q) {
            int e = w * 2 + q;
            int row = e * 16 + lrow;
            gl16(A  + (size_t)(m0 + row) * DD + k0 + (lks ^ swst) * 8, &As[e * 512]);
            gl16(Bt + (size_t)(n0 + row) * DD + k0 + (lks ^ swst) * 8, &Bs[e * 512]);
        }
        __syncthreads();
#pragma unroll
        for (int k16 = 0; k16 < 2; ++k16) {
            int co = ((k16 * 2 + hh) ^ swr) * 8;
            bf16x8 ar0 = *(const bf16x8*)&As[(wr * 64 + l31) * 32 + co];
            bf16x8 ar1 = *(const bf16x8*)&As[(wr * 64 + 32 + l31) * 32 + co];
            bf16x8 br0 = *(const bf16x8*)&Bs[(wc * 64 + l31) * 32 + co];
            bf16x8 br1 = *(const bf16x8*)&Bs[(wc * 64 + 32 + l31) * 32 + co];
            acc[0][0] = __builtin_amdgcn_mfma_f32_32x32x16_bf16(ar0, br0, acc[0][0], 0, 0, 0);
            acc[0][1] = __builtin_amdgcn_mfma_f32_32x32x16_bf16(ar0, br1, acc[0][1], 0, 0, 0);
            acc[1][0] = __builtin_amdgcn_mfma_f32_32x32x16_bf16(ar1, br0, acc[1][0], 0, 0, 0);
            acc[1][1] = __builtin_amdgcn_mfma_f32_32x32x16_bf16(ar1, br1, acc[1][1], 0, 0, 0);
        }
    }

#pragma unroll
    for (int j = 0; j < 2; ++j) {
        int n = n0 + wc * 64 + j * 32 + l31;
        float bv = bias[n];
#pragma unroll
        for (int i = 0; i < 2; ++i) {
#pragma unroll
            for (int r = 0; r < 16; ++r) {
                int m = m0 + wr * 64 + i * 32 + (r & 3) + 8 * (r >> 2) + 4 * hh;
                Out[(size_t)m * DD + n] = acc[i][j][r] + bv;
            }
        }
    }
}

// ---------------------------------------------------------------------------
// MFMA flash attention: 32x32x16 MFMA, 128 q-rows/block, 4 waves.
// Wave w owns q-rows q0+w*32..+31. Swizzled LDS chunks (conflict-free).
// Softmax: fixed reference M=0; l via P*ones MFMA.
//
// Round-5: swapped QK^T (mfma(K,Q) -> S^T: lane = q-col, regs = key-rows);
// P kept in registers, PV A-fragments built with plain-C++ bf16 packing
// (f2bf_fast + shift/or -- byte order by construction; round-4's inline-asm
// v_cvt_pk_bf16_f32 was the prime correctness suspect and is removed) +
// __shfl_xor(32) for the cross-half key exchange. Deletes the Ps LDS
// round-trip entirely. Key mapping per lane (hh=lane>>5): S^T reg r holds
// key (r&3)+8*(r>>2)+4*hh; group g=r>>2 covers keys 8g+4hh..+3. PV frag
// kblk2 needs keys kblk2*16+hh*8..+7: own group (2*kblk2+hh) + partner's
// (lane^32) group (2*kblk2+1-hh). K/V double-buffered as round 3.
// ---------------------------------------------------------------------------
__global__ __launch_bounds__(256, 2) void attn_mfma_kernel(
    const ushort* __restrict__ Q, const ushort* __restrict__ K,
    const ushort* __restrict__ Vt, ushort* __restrict__ Y)
{
    const int bh = blockIdx.y;
    const int qt = gridDim.x - 1 - blockIdx.x;   // heavy tiles first
    const int q0 = qt * 128;
    const int b = bh >> 4, h = bh & 15;

    __shared__ ushort Ks[2][4 * 64 * 32];   // [slot][panel ks: dims ks*32..+32, 64 keys]
    __shared__ ushort Vs[2][2 * 128 * 32];  // [slot][panel kp: keys kp*32..+32, 128 dims]

    const int t = threadIdx.x, w = t >> 6, lane = t & 63;
    const int l31 = lane & 31, hh = lane >> 5;
    const int lrow = lane >> 2, lks = lane & 3;
    const int swst = (lrow >> 1) & 3;    // store-side swizzle key
    const int swr  = (l31 >> 1) & 3;     // read-side swizzle key

    const ushort* Qp = Q  + (size_t)bh * SS * HDIM;
    const ushort* Kp = K  + (size_t)bh * SS * HDIM;
    const ushort* Vp = Vt + (size_t)bh * HDIM * SS;

    // Q fragments to registers: lane q-row = l31, k = kb2*16 + hh*8 + j
    bf16x8 aq[8];
#pragma unroll
    for (int kb2 = 0; kb2 < 8; ++kb2)
        aq[kb2] = *(const bf16x8*)(Qp + (size_t)(q0 + w * 32 + l31) * HDIM + kb2 * 16 + hh * 8);

    bf16x8 ones;
#pragma unroll
    for (int j = 0; j < 8; ++j) ones[j] = (short)0x3F80;  // bf16 1.0

    f32x16 O[4];
#pragma unroll
    for (int nt = 0; nt < 4; ++nt) O[nt] = (f32x16)0.f;
    f32x16 Ol = (f32x16)0.f;

    const int kbdiag = 2 * qt + (w >> 1);
    const int nkb = 2 * qt + 2;
    const bool hi = (hh == 1);
    const int qg = q0 + w * 32 + l31;    // this lane's q-row (S^T column)

    // stage K panel w (dims w*32..+32, 64 keys) + V dims w*32..+32 (both
    // 32-key panels) of tile kb_ into LDS slot s_, swizzled chunks
#define STAGE_KV(kb_, s_) do {                                                  \
    const int kbase_ = (kb_) * 64;                                              \
    _Pragma("unroll")                                                           \
    for (int g = 0; g < 4; ++g) {                                               \
        int key = g * 16 + lrow;                                                \
        gl16(Kp + (size_t)(kbase_ + key) * HDIM + w * 32 + (lks ^ swst) * 8,    \
             &Ks[s_][w * 2048 + g * 512]);                                      \
    }                                                                           \
    _Pragma("unroll")                                                           \
    for (int g = 0; g < 4; ++g) {                                               \
        int pan = g >> 1, sub = g & 1;                                          \
        int dim = w * 32 + sub * 16 + lrow;                                     \
        gl16(Vp + (size_t)dim * SS + kbase_ + pan * 32 + (lks ^ swst) * 8,      \
             &Vs[s_][pan * 4096 + (w * 32 + sub * 16) * 32]);                   \
    }                                                                           \
} while (0)

    STAGE_KV(0, 0);

    for (int kb = 0; kb < nkb; ++kb) {
        const int kbase = kb * 64;
        const int slot = kb & 1;

        if (kb + 1 < nkb) {
            STAGE_KV(kb + 1, slot ^ 1);
            asm volatile("s_waitcnt vmcnt(8)" ::: "memory");  // tile kb landed
        } else {
            asm volatile("s_waitcnt vmcnt(0)" ::: "memory");
        }
        __builtin_amdgcn_s_barrier();   // slot (kb&1) valid workgroup-wide

        const ushort* KsS = Ks[slot];
        const ushort* VsS = Vs[slot];

        if (kb <= kbdiag) {
            // S^T = K Q^T, two 32-key m-tiles (swapped operands: A=K, B=Q)
            f32x16 st0 = (f32x16)0.f, st1 = (f32x16)0.f;
            __builtin_amdgcn_s_setprio(1);
#pragma unroll
            for (int kb2 = 0; kb2 < 8; ++kb2) {
                int co = (((kb2 & 1) * 2 + hh) ^ swr) * 8;
                bf16x8 bk0 = *(const bf16x8*)&KsS[(kb2 >> 1) * 2048 + l31 * 32 + co];
                bf16x8 bk1 = *(const bf16x8*)&KsS[(kb2 >> 1) * 2048 + (32 + l31) * 32 + co];
                st0 = __builtin_amdgcn_mfma_f32_32x32x16_bf16(bk0, aq[kb2], st0, 0, 0, 0);
                st1 = __builtin_amdgcn_mfma_f32_32x32x16_bf16(bk1, aq[kb2], st1, 0, 0, 0);
            }
            __builtin_amdgcn_s_setprio(0);

            if (kb == kbdiag) {   // diagonal: causal mask (key > q-row)
#pragma unroll
                for (int r = 0; r < 16; ++r) {
                    int keyr = kbase + (r & 3) + 8 * (r >> 2) + 4 * hh;
                    if (keyr > qg)      st0[r] = -1e30f;
                    if (keyr + 32 > qg) st1[r] = -1e30f;
                }
            }

            // per 32-key half: exp2 -> pack bf16 pairs (plain C++) ->
            // shfl_xor(32) cross-half exchange -> PV A-frags
#pragma unroll
            for (int half = 0; half < 2; ++half) {
                float p[16];
#pragma unroll
                for (int r = 0; r < 16; ++r)
                    p[r] = __builtin_amdgcn_exp2f((half == 0) ? st0[r] : st1[r]);
                // word wX[g]: keys 8g+4hh + {2X, 2X+1}; low ushort = lower key
                uint w0[4], w1[4];
#pragma unroll
                for (int g = 0; g < 4; ++g) {
                    w0[g] = (uint)f2bf_fast(p[4 * g])
                          | ((uint)f2bf_fast(p[4 * g + 1]) << 16);
                    w1[g] = (uint)f2bf_fast(p[4 * g + 2])
                          | ((uint)f2bf_fast(p[4 * g + 3]) << 16);
                }
#pragma unroll
                for (int kblk2 = 0; kblk2 < 2; ++kblk2) {
                    // own group = 2*kblk2+hh ; send group = 2*kblk2+1-hh
                    uint own0 = hi ? w0[2 * kblk2 + 1] : w0[2 * kblk2];
                    uint own1 = hi ? w1[2 * kblk2 + 1] : w1[2 * kblk2];
                    uint snd0 = hi ? w0[2 * kblk2]     : w0[2 * kblk2 + 1];
                    uint snd1 = hi ? w1[2 * kblk2]     : w1[2 * kblk2 + 1];
                    uint ps0 = (uint)__shfl_xor((int)snd0, 32, 64);
                    uint ps1 = (uint)__shfl_xor((int)snd1, 32, 64);
                    union { uint u[4]; bf16x8 v; } fr;
                    fr.u[0] = hi ? ps0 : own0;   // keys kblk2*16+hh*8 + {0,1}
                    fr.u[1] = hi ? ps1 : own1;   // + {2,3}
                    fr.u[2] = hi ? own0 : ps0;   // + {4,5}
                    fr.u[3] = hi ? own1 : ps1;   // + {6,7}
                    int co = ((kblk2 * 2 + hh) ^ swr) * 8;
                    __builtin_amdgcn_s_setprio(1);
#pragma unroll
                    for (int nt = 0; nt < 4; ++nt) {
                        bf16x8 bv = *(const bf16x8*)&VsS[half * 4096 + (nt * 32 + l31) * 32 + co];
                        O[nt] = __builtin_amdgcn_mfma_f32_32x32x16_bf16(fr.v, bv, O[nt], 0, 0, 0);
                    }
                    Ol = __builtin_amdgcn_mfma_f32_32x32x16_bf16(fr.v, ones, Ol, 0, 0, 0);
                    __builtin_amdgcn_s_setprio(0);
                }
            }
        }
        __builtin_amdgcn_s_barrier();   // WAR guard before slot reuse
    }
#undef STAGE_KV

    // epilogue: divide by l, write Y[b,s,h*128+hd]
#pragma unroll
    for (int r = 0; r < 16; ++r) {
        int s = q0 + w * 32 + (r & 3) + 8 * (r >> 2) + 4 * hh;
        float inv = 1.0f / Ol[r];
        size_t base = ((size_t)(b * SS + s)) * DD + h * HDIM;
#pragma unroll
        for (int nt = 0; nt < 4; ++nt)
            Y[base + nt * 32 + l31] = f2bf(O[nt][r] * inv);
    }
}

// ---------------------------------------------------------------------------
extern "C" void kernel_launch(void* const* d_in, const int* in_sizes, int n_in,
                              void* d_out, int out_size, void* d_ws, size_t ws_size,
                              hipStream_t stream) {
    const float* x     = (const float*)d_in[0];
    const float* w_qkv = (const float*)d_in[1];
    const float* b_qkv = (const float*)d_in[2];
    const float* w_out = (const float*)d_in[3];
    const float* b_out = (const float*)d_in[4];
    float* out = (float*)d_out;

    ushort* ws  = (ushort*)d_ws;
    ushort* xb  = ws;                      // 8,388,608
    ushort* wtq = xb + 8388608;            // 12,582,912
    ushort* wto = wtq + 12582912;          // 4,194,304
    ushort* q   = wto + 4194304;           // 8,388,608
    ushort* k   = q + 8388608;
    ushort* v   = k + 8388608;             // [B,H,S,HD]
    ushort* vt  = v + 8388608;             // [B,H,HD,S]
    ushort* y   = vt + 8388608;

    cast_x_kernel<<<4096, 256, 0, stream>>>(x, xb);
    transpose_cast_kernel<<<dim3(192, 64), 256, 0, stream>>>(w_qkv, wtq, DD, 3 * DD);
    transpose_cast_kernel<<<dim3(64, 64), 256, 0, stream>>>(w_out, wto, DD, DD);
    gemm_qkv_kernel<<<dim3(48, 32), 256, 0, stream>>>(xb, wtq, b_qkv, q, k, v);
    transpose_v_kernel<<<dim3(64, 4, 32), 256, 0, stream>>>(v, vt);
    attn_mfma_kernel<<<dim3(16, 32), 256, 0, stream>>>(q, k, vt, y);
    gemm_out_kernel<<<dim3(16, 32), 256, 0, stream>>>(y, wto, b_out, out);
}

// Round 6
// 374.493 us; speedup vs baseline: 1.0852x; 1.0852x over previous
//
#include <hip/hip_runtime.h>
#include <hip/hip_bf16.h>
#include <cstdint>
#include <cstddef>

#define BB 2
#define SS 2048
#define DD 2048
#define HH 16
#define HDIM 128
// 1/sqrt(128) * log2(e): folded into Q so softmax uses exp2 directly
#define QSCALE 0.12751743f

typedef short bf16x8 __attribute__((ext_vector_type(8)));
typedef float f32x4 __attribute__((ext_vector_type(4)));
typedef float f32x16 __attribute__((ext_vector_type(16)));

__device__ __forceinline__ ushort f2bf(float f) {
    union { float f; uint32_t u; } v; v.f = f;
    uint32_t u = v.u;
    u += 0x7fffu + ((u >> 16) & 1u);
    return (ushort)(u >> 16);
}

// cheap round-half-up f32->bf16 (2 VALU ops); fine for nonnegative p
__device__ __forceinline__ ushort f2bf_fast(float f) {
    union { float f; uint32_t u; } v; v.f = f;
    return (ushort)((v.u + 0x8000u) >> 16);
}

// async 16B global -> LDS (wave-uniform LDS base + lane*16)
__device__ __forceinline__ void gl16(const ushort* g, ushort* l) {
    __builtin_amdgcn_global_load_lds(
        (const __attribute__((address_space(1))) unsigned int*)g,
        (__attribute__((address_space(3))) unsigned int*)l,
        16, 0, 0);
}

// ---------------------------------------------------------------------------
// Prep kernels
// ---------------------------------------------------------------------------
__global__ __launch_bounds__(256) void cast_x_kernel(
    const float* __restrict__ X, ushort* __restrict__ Xb)
{
    size_t idx = ((size_t)blockIdx.x * 256 + threadIdx.x) * 8;
    float4 a = *(const float4*)(X + idx);
    float4 b = *(const float4*)(X + idx + 4);
    ushort4 o0, o1;
    o0.x = f2bf(a.x); o0.y = f2bf(a.y); o0.z = f2bf(a.z); o0.w = f2bf(a.w);
    o1.x = f2bf(b.x); o1.y = f2bf(b.y); o1.z = f2bf(b.z); o1.w = f2bf(b.w);
    *(ushort4*)(Xb + idx) = o0;
    *(ushort4*)(Xb + idx + 4) = o1;
}

// W fp32 [K][N] row-major -> Wt bf16 [N][K]
__global__ __launch_bounds__(256) void transpose_cast_kernel(
    const float* __restrict__ W, ushort* __restrict__ Wt, int K, int N)
{
    __shared__ ushort tile[32][36];
    const int n0 = blockIdx.x * 32;
    const int k0 = blockIdx.y * 32;
    const int t = threadIdx.x;
    const int r = t >> 3;
    const int c = (t & 7) * 4;
    float4 a = *(const float4*)(W + (size_t)(k0 + r) * N + n0 + c);
    tile[r][c + 0] = f2bf(a.x); tile[r][c + 1] = f2bf(a.y);
    tile[r][c + 2] = f2bf(a.z); tile[r][c + 3] = f2bf(a.w);
    __syncthreads();
    ushort4 o;
    o.x = tile[c + 0][r]; o.y = tile[c + 1][r];
    o.z = tile[c + 2][r]; o.w = tile[c + 3][r];
    *(ushort4*)(Wt + (size_t)(n0 + r) * K + k0 + c) = o;
}

// V bf16 [BH][S][HD] -> Vt bf16 [BH][HD][S]
__global__ __launch_bounds__(256) void transpose_v_kernel(
    const ushort* __restrict__ V, ushort* __restrict__ Vt)
{
    __shared__ ushort tile[32][36];
    const int s0 = blockIdx.x * 32;
    const int h0 = blockIdx.y * 32;
    const int bh = blockIdx.z;
    const ushort* Vp = V + (size_t)bh * SS * HDIM;
    ushort* Vtp = Vt + (size_t)bh * HDIM * SS;
    const int t = threadIdx.x;
    const int r = t >> 3;
    const int c = (t & 7) * 4;
    *(ushort4*)&tile[r][c] = *(const ushort4*)(Vp + (size_t)(s0 + r) * HDIM + h0 + c);
    __syncthreads();
    ushort4 o;
    o.x = tile[c + 0][r]; o.y = tile[c + 1][r];
    o.z = tile[c + 2][r]; o.w = tile[c + 3][r];
    *(ushort4*)(Vtp + (size_t)(h0 + r) * SS + s0 + c) = o;
}

// ---------------------------------------------------------------------------
// MFMA GEMM: C[M,N] = A[M,K] @ Bt[N,K]^T, 128x128 tile, BK=64 (m97-class:
// half the barrier drains of BK=32, 16 MFMA per barrier). Rows are 128 B =
// 2 halves x 4 chunks of 16 B; chunk-in-half swizzle key = (row>>1)&3
// (store via inverse-swizzled global source, read via XOR) -> conflict-free
// column ds_read_b128. LDS 2 x 16 KB.
// ---------------------------------------------------------------------------
__global__ __launch_bounds__(256) void gemm_qkv_kernel(
    const ushort* __restrict__ A, const ushort* __restrict__ Bt,
    const float* __restrict__ bias,
    ushort* __restrict__ Qo, ushort* __restrict__ Ko, ushort* __restrict__ Vo)
{
    const int n0 = blockIdx.x * 128;
    const int m0 = blockIdx.y * 128;
    __shared__ ushort As[128 * 64];
    __shared__ ushort Bs[128 * 64];
    const int t = threadIdx.x, w = t >> 6, lane = t & 63;
    const int l31 = lane & 31, hh = lane >> 5;
    const int wr = w >> 1, wc = w & 1;
    const int swr = (l31 >> 1) & 3;       // read-side swizzle key

    // staging: call q covers rows (w*4+q)*8 .. +7; lane -> subrow lane>>3,
    // k-half (lane>>2)&1, chunk lane&3; store key = (row>>1)&3 = (lane>>4)&3
    const int rt   = lane >> 3;
    const int kh   = (lane >> 2) & 1;
    const int ch   = lane & 3;
    const int skey = (lane >> 4) & 3;
    const int koff = kh * 32 + ((ch ^ skey) * 8);

    f32x16 acc[2][2];
#pragma unroll
    for (int i = 0; i < 2; ++i)
#pragma unroll
        for (int j = 0; j < 2; ++j) acc[i][j] = (f32x16)0.f;

    for (int k0 = 0; k0 < DD; k0 += 64) {
        __syncthreads();
#pragma unroll
        for (int q = 0; q < 4; ++q) {
            int R = (w * 4 + q) * 8 + rt;
            gl16(A  + (size_t)(m0 + R) * DD + k0 + koff, &As[(w * 4 + q) * 512]);
            gl16(Bt + (size_t)(n0 + R) * DD + k0 + koff, &Bs[(w * 4 + q) * 512]);
        }
        __syncthreads();   // compiler emits vmcnt(0) drain here (m97 semantics)
#pragma unroll
        for (int k16 = 0; k16 < 4; ++k16) {
            int co = (k16 >> 1) * 32 + ((((k16 & 1) * 2 + hh) ^ swr) * 8);
            bf16x8 ar0 = *(const bf16x8*)&As[(wr * 64 + l31) * 64 + co];
            bf16x8 ar1 = *(const bf16x8*)&As[(wr * 64 + 32 + l31) * 64 + co];
            bf16x8 br0 = *(const bf16x8*)&Bs[(wc * 64 + l31) * 64 + co];
            bf16x8 br1 = *(const bf16x8*)&Bs[(wc * 64 + 32 + l31) * 64 + co];
            acc[0][0] = __builtin_amdgcn_mfma_f32_32x32x16_bf16(ar0, br0, acc[0][0], 0, 0, 0);
            acc[0][1] = __builtin_amdgcn_mfma_f32_32x32x16_bf16(ar0, br1, acc[0][1], 0, 0, 0);
            acc[1][0] = __builtin_amdgcn_mfma_f32_32x32x16_bf16(ar1, br0, acc[1][0], 0, 0, 0);
            acc[1][1] = __builtin_amdgcn_mfma_f32_32x32x16_bf16(ar1, br1, acc[1][1], 0, 0, 0);
        }
    }

    // Epilogue: bias, fold QSCALE into Q, scatter bf16 into [B,H,S,HD]
    const int bidx = m0 >> 11;
    const int which = n0 >> 11;           // block-uniform (n0 % 128 == 0)
    ushort* dst = (which == 0) ? Qo : ((which == 1) ? Ko : Vo);
    const float sc = (which == 0) ? QSCALE : 1.0f;
#pragma unroll
    for (int j = 0; j < 2; ++j) {
        int n = n0 + wc * 64 + j * 32 + l31;
        int c = n & 2047, h = c >> 7, hd = c & 127;
        float bv = bias[n];
        size_t base = ((size_t)(bidx * HH + h) * SS) * HDIM + hd;
#pragma unroll
        for (int i = 0; i < 2; ++i) {
#pragma unroll
            for (int r = 0; r < 16; ++r) {
                int s = (m0 & 2047) + wr * 64 + i * 32 + (r & 3) + 8 * (r >> 2) + 4 * hh;
                dst[base + (size_t)s * HDIM] = f2bf((acc[i][j][r] + bv) * sc);
            }
        }
    }
}

__global__ __launch_bounds__(256) void gemm_out_kernel(
    const ushort* __restrict__ A, const ushort* __restrict__ Bt,
    const float* __restrict__ bias, float* __restrict__ Out)
{
    const int n0 = blockIdx.x * 128;
    const int m0 = blockIdx.y * 128;
    __shared__ ushort As[128 * 64];
    __shared__ ushort Bs[128 * 64];
    const int t = threadIdx.x, w = t >> 6, lane = t & 63;
    const int l31 = lane & 31, hh = lane >> 5;
    const int wr = w >> 1, wc = w & 1;
    const int swr = (l31 >> 1) & 3;

    const int rt   = lane >> 3;
    const int kh   = (lane >> 2) & 1;
    const int ch   = lane & 3;
    const int skey = (lane >> 4) & 3;
    const int koff = kh * 32 + ((ch ^ skey) * 8);

    f32x16 acc[2][2];
#pragma unroll
    for (int i = 0; i < 2; ++i)
#pragma unroll
        for (int j = 0; j < 2; ++j) acc[i][j] = (f32x16)0.f;

    for (int k0 = 0; k0 < DD; k0 += 64) {
        __syncthreads();
#pragma unroll
        for (int q = 0; q < 4; ++q) {
            int R = (w * 4 + q) * 8 + rt;
            gl16(A  + (size_t)(m0 + R) * DD + k0 + koff, &As[(w * 4 + q) * 512]);
            gl16(Bt + (size_t)(n0 + R) * DD + k0 + koff, &Bs[(w * 4 + q) * 512]);
        }
        __syncthreads();
#pragma unroll
        for (int k16 = 0; k16 < 4; ++k16) {
            int co = (k16 >> 1) * 32 + ((((k16 & 1) * 2 + hh) ^ swr) * 8);
            bf16x8 ar0 = *(const bf16x8*)&As[(wr * 64 + l31) * 64 + co];
            bf16x8 ar1 = *(const bf16x8*)&As[(wr * 64 + 32 + l31) * 64 + co];
            bf16x8 br0 = *(const bf16x8*)&Bs[(wc * 64 + l31) * 64 + co];
            bf16x8 br1 = *(const bf16x8*)&Bs[(wc * 64 + 32 + l31) * 64 + co];
            acc[0][0] = __builtin_amdgcn_mfma_f32_32x32x16_bf16(ar0, br0, acc[0][0], 0, 0, 0);
            acc[0][1] = __builtin_amdgcn_mfma_f32_32x32x16_bf16(ar0, br1, acc[0][1], 0, 0, 0);
            acc[1][0] = __builtin_amdgcn_mfma_f32_32x32x16_bf16(ar1, br0, acc[1][0], 0, 0, 0);
            acc[1][1] = __builtin_amdgcn_mfma_f32_32x32x16_bf16(ar1, br1, acc[1][1], 0, 0, 0);
        }
    }

#pragma unroll
    for (int j = 0; j < 2; ++j) {
        int n = n0 + wc * 64 + j * 32 + l31;
        float bv = bias[n];
#pragma unroll
        for (int i = 0; i < 2; ++i) {
#pragma unroll
            for (int r = 0; r < 16; ++r) {
                int m = m0 + wr * 64 + i * 32 + (r & 3) + 8 * (r >> 2) + 4 * hh;
                Out[(size_t)m * DD + n] = acc[i][j][r] + bv;
            }
        }
    }
}

// ---------------------------------------------------------------------------
// MFMA flash attention: 32x32x16 MFMA, 128 q-rows/block, 4 waves.
// Swapped QK^T + in-register softmax (round 5), K/V double-buffered.
//
// Round-6 change: LOAD-BALANCED BLOCK MAP. Work per block ~ 2*qt+2 (2..32
// tile-iters). Old grid (16,32) paired fid and fid+256 with IDENTICAL qt on
// one CU (both heavy or both light) -> makespan ~ 2x heaviest = 64 iters vs
// mean 34. New flat-512 map: fid and fid+256 have qt summing to 15, so every
// CU pair sums to 34 iters under the fid%256 round-robin heuristic; any
// other assignment still sees interleaved heavy/light. Pure index remap.
// ---------------------------------------------------------------------------
__global__ __launch_bounds__(256, 2) void attn_mfma_kernel(
    const ushort* __restrict__ Q, const ushort* __restrict__ K,
    const ushort* __restrict__ Vt, ushort* __restrict__ Y)
{
    const int fid = blockIdx.x;
    const int halfg = fid >> 8, rg = fid & 255;
    const int qt = halfg ? (rg & 15) : (15 - (rg & 15));
    const int bh = (halfg << 4) | (rg >> 4);
    const int q0 = qt * 128;
    const int b = bh >> 4, h = bh & 15;

    __shared__ ushort Ks[2][4 * 64 * 32];   // [slot][panel ks: dims ks*32..+32, 64 keys]
    __shared__ ushort Vs[2][2 * 128 * 32];  // [slot][panel kp: keys kp*32..+32, 128 dims]

    const int t = threadIdx.x, w = t >> 6, lane = t & 63;
    const int l31 = lane & 31, hh = lane >> 5;
    const int lrow = lane >> 2, lks = lane & 3;
    const int swst = (lrow >> 1) & 3;    // store-side swizzle key
    const int swr  = (l31 >> 1) & 3;     // read-side swizzle key

    const ushort* Qp = Q  + (size_t)bh * SS * HDIM;
    const ushort* Kp = K  + (size_t)bh * SS * HDIM;
    const ushort* Vp = Vt + (size_t)bh * HDIM * SS;

    // Q fragments to registers: lane q-row = l31, k = kb2*16 + hh*8 + j
    bf16x8 aq[8];
#pragma unroll
    for (int kb2 = 0; kb2 < 8; ++kb2)
        aq[kb2] = *(const bf16x8*)(Qp + (size_t)(q0 + w * 32 + l31) * HDIM + kb2 * 16 + hh * 8);

    bf16x8 ones;
#pragma unroll
    for (int j = 0; j < 8; ++j) ones[j] = (short)0x3F80;  // bf16 1.0

    f32x16 O[4];
#pragma unroll
    for (int nt = 0; nt < 4; ++nt) O[nt] = (f32x16)0.f;
    f32x16 Ol = (f32x16)0.f;

    const int kbdiag = 2 * qt + (w >> 1);
    const int nkb = 2 * qt + 2;
    const bool hi = (hh == 1);
    const int qg = q0 + w * 32 + l31;    // this lane's q-row (S^T column)

    // stage K panel w (dims w*32..+32, 64 keys) + V dims w*32..+32 (both
    // 32-key panels) of tile kb_ into LDS slot s_, swizzled chunks
#define STAGE_KV(kb_, s_) do {                                                  \
    const int kbase_ = (kb_) * 64;                                              \
    _Pragma("unroll")                                                           \
    for (int g = 0; g < 4; ++g) {                                               \
        int key = g * 16 + lrow;                                                \
        gl16(Kp + (size_t)(kbase_ + key) * HDIM + w * 32 + (lks ^ swst) * 8,    \
             &Ks[s_][w * 2048 + g * 512]);                                      \
    }                                                                           \
    _Pragma("unroll")                                                           \
    for (int g = 0; g < 4; ++g) {                                               \
        int pan = g >> 1, sub = g & 1;                                          \
        int dim = w * 32 + sub * 16 + lrow;                                     \
        gl16(Vp + (size_t)dim * SS + kbase_ + pan * 32 + (lks ^ swst) * 8,      \
             &Vs[s_][pan * 4096 + (w * 32 + sub * 16) * 32]);                   \
    }                                                                           \
} while (0)

    STAGE_KV(0, 0);

    for (int kb = 0; kb < nkb; ++kb) {
        const int kbase = kb * 64;
        const int slot = kb & 1;

        if (kb + 1 < nkb) {
            STAGE_KV(kb + 1, slot ^ 1);
            asm volatile("s_waitcnt vmcnt(8)" ::: "memory");  // tile kb landed
        } else {
            asm volatile("s_waitcnt vmcnt(0)" ::: "memory");
        }
        __builtin_amdgcn_s_barrier();   // slot (kb&1) valid workgroup-wide

        const ushort* KsS = Ks[slot];
        const ushort* VsS = Vs[slot];

        if (kb <= kbdiag) {
            // S^T = K Q^T, two 32-key m-tiles (swapped operands: A=K, B=Q)
            f32x16 st0 = (f32x16)0.f, st1 = (f32x16)0.f;
            __builtin_amdgcn_s_setprio(1);
#pragma unroll
            for (int kb2 = 0; kb2 < 8; ++kb2) {
                int co = (((kb2 & 1) * 2 + hh) ^ swr) * 8;
                bf16x8 bk0 = *(const bf16x8*)&KsS[(kb2 >> 1) * 2048 + l31 * 32 + co];
                bf16x8 bk1 = *(const bf16x8*)&KsS[(kb2 >> 1) * 2048 + (32 + l31) * 32 + co];
                st0 = __builtin_amdgcn_mfma_f32_32x32x16_bf16(bk0, aq[kb2], st0, 0, 0, 0);
                st1 = __builtin_amdgcn_mfma_f32_32x32x16_bf16(bk1, aq[kb2], st1, 0, 0, 0);
            }
            __builtin_amdgcn_s_setprio(0);

            if (kb == kbdiag) {   // diagonal: causal mask (key > q-row)
#pragma unroll
                for (int r = 0; r < 16; ++r) {
                    int keyr = kbase + (r & 3) + 8 * (r >> 2) + 4 * hh;
                    if (keyr > qg)      st0[r] = -1e30f;
                    if (keyr + 32 > qg) st1[r] = -1e30f;
                }
            }

            // per 32-key half: exp2 -> pack bf16 pairs (plain C++) ->
            // shfl_xor(32) cross-half exchange -> PV A-frags
#pragma unroll
            for (int half = 0; half < 2; ++half) {
                float p[16];
#pragma unroll
                for (int r = 0; r < 16; ++r)
                    p[r] = __builtin_amdgcn_exp2f((half == 0) ? st0[r] : st1[r]);
                // word wX[g]: keys 8g+4hh + {2X, 2X+1}; low ushort = lower key
                uint w0[4], w1[4];
#pragma unroll
                for (int g = 0; g < 4; ++g) {
                    w0[g] = (uint)f2bf_fast(p[4 * g])
                          | ((uint)f2bf_fast(p[4 * g + 1]) << 16);
                    w1[g] = (uint)f2bf_fast(p[4 * g + 2])
                          | ((uint)f2bf_fast(p[4 * g + 3]) << 16);
                }
#pragma unroll
                for (int kblk2 = 0; kblk2 < 2; ++kblk2) {
                    // own group = 2*kblk2+hh ; send group = 2*kblk2+1-hh
                    uint own0 = hi ? w0[2 * kblk2 + 1] : w0[2 * kblk2];
                    uint own1 = hi ? w1[2 * kblk2 + 1] : w1[2 * kblk2];
                    uint snd0 = hi ? w0[2 * kblk2]     : w0[2 * kblk2 + 1];
                    uint snd1 = hi ? w1[2 * kblk2]     : w1[2 * kblk2 + 1];
                    uint ps0 = (uint)__shfl_xor((int)snd0, 32, 64);
                    uint ps1 = (uint)__shfl_xor((int)snd1, 32, 64);
                    union { uint u[4]; bf16x8 v; } fr;
                    fr.u[0] = hi ? ps0 : own0;   // keys kblk2*16+hh*8 + {0,1}
                    fr.u[1] = hi ? ps1 : own1;   // + {2,3}
                    fr.u[2] = hi ? own0 : ps0;   // + {4,5}
                    fr.u[3] = hi ? own1 : ps1;   // + {6,7}
                    int co = ((kblk2 * 2 + hh) ^ swr) * 8;
                    __builtin_amdgcn_s_setprio(1);
#pragma unroll
                    for (int nt = 0; nt < 4; ++nt) {
                        bf16x8 bv = *(const bf16x8*)&VsS[half * 4096 + (nt * 32 + l31) * 32 + co];
                        O[nt] = __builtin_amdgcn_mfma_f32_32x32x16_bf16(fr.v, bv, O[nt], 0, 0, 0);
                    }
                    Ol = __builtin_amdgcn_mfma_f32_32x32x16_bf16(fr.v, ones, Ol, 0, 0, 0);
                    __builtin_amdgcn_s_setprio(0);
                }
            }
        }
        __builtin_amdgcn_s_barrier();   // WAR guard before slot reuse
    }
#undef STAGE_KV

    // epilogue: divide by l, write Y[b,s,h*128+hd]
#pragma unroll
    for (int r = 0; r < 16; ++r) {
        int s = q0 + w * 32 + (r & 3) + 8 * (r >> 2) + 4 * hh;
        float inv = 1.0f / Ol[r];
        size_t base = ((size_t)(b * SS + s)) * DD + h * HDIM;
#pragma unroll
        for (int nt = 0; nt < 4; ++nt)
            Y[base + nt * 32 + l31] = f2bf(O[nt][r] * inv);
    }
}

// ---------------------------------------------------------------------------
extern "C" void kernel_launch(void* const* d_in, const int* in_sizes, int n_in,
                              void* d_out, int out_size, void* d_ws, size_t ws_size,
                              hipStream_t stream) {
    const float* x     = (const float*)d_in[0];
    const float* w_qkv = (const float*)d_in[1];
    const float* b_qkv = (const float*)d_in[2];
    const float* w_out = (const float*)d_in[3];
    const float* b_out = (const float*)d_in[4];
    float* out = (float*)d_out;

    ushort* ws  = (ushort*)d_ws;
    ushort* xb  = ws;                      // 8,388,608
    ushort* wtq = xb + 8388608;            // 12,582,912
    ushort* wto = wtq + 12582912;          // 4,194,304
    ushort* q   = wto + 4194304;           // 8,388,608
    ushort* k   = q + 8388608;
    ushort* v   = k + 8388608;             // [B,H,S,HD]
    ushort* vt  = v + 8388608;             // [B,H,HD,S]
    ushort* y   = vt + 8388608;

    cast_x_kernel<<<4096, 256, 0, stream>>>(x, xb);
    transpose_cast_kernel<<<dim3(192, 64), 256, 0, stream>>>(w_qkv, wtq, DD, 3 * DD);
    transpose_cast_kernel<<<dim3(64, 64), 256, 0, stream>>>(w_out, wto, DD, DD);
    gemm_qkv_kernel<<<dim3(48, 32), 256, 0, stream>>>(xb, wtq, b_qkv, q, k, v);
    transpose_v_kernel<<<dim3(64, 4, 32), 256, 0, stream>>>(v, vt);
    attn_mfma_kernel<<<dim3(512), 256, 0, stream>>>(q, k, vt, y);
    gemm_out_kernel<<<dim3(16, 32), 256, 0, stream>>>(y, wto, b_out, out);
}

// Round 8
// 373.195 us; speedup vs baseline: 1.0890x; 1.0035x over previous
//
#include <hip/hip_runtime.h>
#include <hip/hip_bf16.h>
#include <cstdint>
#include <cstddef>

#define BB 2
#define SS 2048
#define DD 2048
#define HH 16
#define HDIM 128
// 1/sqrt(128) * log2(e): folded into Q so softmax uses exp2 directly
#define QSCALE 0.12751743f

typedef short bf16x8 __attribute__((ext_vector_type(8)));
typedef float f32x4 __attribute__((ext_vector_type(4)));
typedef float f32x16 __attribute__((ext_vector_type(16)));

__device__ __forceinline__ ushort f2bf(float f) {
    union { float f; uint32_t u; } v; v.f = f;
    uint32_t u = v.u;
    u += 0x7fffu + ((u >> 16) & 1u);
    return (ushort)(u >> 16);
}

// cheap round-half-up f32->bf16 (2 VALU ops); fine for nonnegative p
__device__ __forceinline__ ushort f2bf_fast(float f) {
    union { float f; uint32_t u; } v; v.f = f;
    return (ushort)((v.u + 0x8000u) >> 16);
}

// async 16B global -> LDS (wave-uniform LDS base + lane*16)
__device__ __forceinline__ void gl16(const ushort* g, ushort* l) {
    __builtin_amdgcn_global_load_lds(
        (const __attribute__((address_space(1))) unsigned int*)g,
        (__attribute__((address_space(3))) unsigned int*)l,
        16, 0, 0);
}

// ---------------------------------------------------------------------------
// Prep kernels
// ---------------------------------------------------------------------------
__global__ __launch_bounds__(256) void cast_x_kernel(
    const float* __restrict__ X, ushort* __restrict__ Xb)
{
    size_t idx = ((size_t)blockIdx.x * 256 + threadIdx.x) * 8;
    float4 a = *(const float4*)(X + idx);
    float4 b = *(const float4*)(X + idx + 4);
    ushort4 o0, o1;
    o0.x = f2bf(a.x); o0.y = f2bf(a.y); o0.z = f2bf(a.z); o0.w = f2bf(a.w);
    o1.x = f2bf(b.x); o1.y = f2bf(b.y); o1.z = f2bf(b.z); o1.w = f2bf(b.w);
    *(ushort4*)(Xb + idx) = o0;
    *(ushort4*)(Xb + idx + 4) = o1;
}

// W fp32 [K][N] row-major -> Wt bf16 [N][K]
__global__ __launch_bounds__(256) void transpose_cast_kernel(
    const float* __restrict__ W, ushort* __restrict__ Wt, int K, int N)
{
    __shared__ ushort tile[32][36];
    const int n0 = blockIdx.x * 32;
    const int k0 = blockIdx.y * 32;
    const int t = threadIdx.x;
    const int r = t >> 3;
    const int c = (t & 7) * 4;
    float4 a = *(const float4*)(W + (size_t)(k0 + r) * N + n0 + c);
    tile[r][c + 0] = f2bf(a.x); tile[r][c + 1] = f2bf(a.y);
    tile[r][c + 2] = f2bf(a.z); tile[r][c + 3] = f2bf(a.w);
    __syncthreads();
    ushort4 o;
    o.x = tile[c + 0][r]; o.y = tile[c + 1][r];
    o.z = tile[c + 2][r]; o.w = tile[c + 3][r];
    *(ushort4*)(Wt + (size_t)(n0 + r) * K + k0 + c) = o;
}

// V bf16 [BH][S][HD] -> Vt bf16 [BH][HD][S]
__global__ __launch_bounds__(256) void transpose_v_kernel(
    const ushort* __restrict__ V, ushort* __restrict__ Vt)
{
    __shared__ ushort tile[32][36];
    const int s0 = blockIdx.x * 32;
    const int h0 = blockIdx.y * 32;
    const int bh = blockIdx.z;
    const ushort* Vp = V + (size_t)bh * SS * HDIM;
    ushort* Vtp = Vt + (size_t)bh * HDIM * SS;
    const int t = threadIdx.x;
    const int r = t >> 3;
    const int c = (t & 7) * 4;
    *(ushort4*)&tile[r][c] = *(const ushort4*)(Vp + (size_t)(s0 + r) * HDIM + h0 + c);
    __syncthreads();
    ushort4 o;
    o.x = tile[c + 0][r]; o.y = tile[c + 1][r];
    o.z = tile[c + 2][r]; o.w = tile[c + 3][r];
    *(ushort4*)(Vtp + (size_t)(h0 + r) * SS + s0 + c) = o;
}

// ---------------------------------------------------------------------------
// MFMA GEMM: C[M,N] = A[M,K] @ Bt[N,K]^T, 128x128 tile, BK=64.
// FULL 3-bit granule swizzle. Rows are 128 B = 8 granules of 16 B;
// phys granule = logical ^ (row&7) (store via inverse-swizzled global source,
// read via XOR). Column ds_read_b128: 32 lanes -> 8 spans x 4 lanes = 4-way
// (the b128 floor), vs old 4-value key's 8-way. Was 17% of kernel cycles
// in SQ_LDS_BANK_CONFLICT.
// ---------------------------------------------------------------------------
__global__ __launch_bounds__(256) void gemm_qkv_kernel(
    const ushort* __restrict__ A, const ushort* __restrict__ Bt,
    const float* __restrict__ bias,
    ushort* __restrict__ Qo, ushort* __restrict__ Ko, ushort* __restrict__ Vo)
{
    const int n0 = blockIdx.x * 128;
    const int m0 = blockIdx.y * 128;
    __shared__ ushort As[128 * 64];
    __shared__ ushort Bs[128 * 64];
    const int t = threadIdx.x, w = t >> 6, lane = t & 63;
    const int l31 = lane & 31, hh = lane >> 5;
    const int wr = w >> 1, wc = w & 1;
    const int l7 = l31 & 7;               // read-row mod 8 (all frag rows ≡ l31 mod 8)

    // staging: call q covers rows (w*4+q)*8..+7; lane -> subrow lane>>3 (=row&7),
    // phys granule lane&7; fetch logical granule (lane&7)^(lane>>3)
    const int rt   = lane >> 3;
    const int koff = ((lane & 7) ^ rt) * 8;   // ushorts

    f32x16 acc[2][2];
#pragma unroll
    for (int i = 0; i < 2; ++i)
#pragma unroll
        for (int j = 0; j < 2; ++j) acc[i][j] = (f32x16)0.f;

    for (int k0 = 0; k0 < DD; k0 += 64) {
        __syncthreads();
#pragma unroll
        for (int q = 0; q < 4; ++q) {
            int R = (w * 4 + q) * 8 + rt;
            gl16(A  + (size_t)(m0 + R) * DD + k0 + koff, &As[(w * 4 + q) * 512]);
            gl16(Bt + (size_t)(n0 + R) * DD + k0 + koff, &Bs[(w * 4 + q) * 512]);
        }
        __syncthreads();
#pragma unroll
        for (int k16 = 0; k16 < 4; ++k16) {
            // logical granule lg: lg*8 = (k16>>1)*32 + (k16&1)*16 + hh*8
            int lg = (k16 >> 1) * 4 + (k16 & 1) * 2 + hh;
            int co = (lg ^ l7) * 8;
            bf16x8 ar0 = *(const bf16x8*)&As[(wr * 64 + l31) * 64 + co];
            bf16x8 ar1 = *(const bf16x8*)&As[(wr * 64 + 32 + l31) * 64 + co];
            bf16x8 br0 = *(const bf16x8*)&Bs[(wc * 64 + l31) * 64 + co];
            bf16x8 br1 = *(const bf16x8*)&Bs[(wc * 64 + 32 + l31) * 64 + co];
            acc[0][0] = __builtin_amdgcn_mfma_f32_32x32x16_bf16(ar0, br0, acc[0][0], 0, 0, 0);
            acc[0][1] = __builtin_amdgcn_mfma_f32_32x32x16_bf16(ar0, br1, acc[0][1], 0, 0, 0);
            acc[1][0] = __builtin_amdgcn_mfma_f32_32x32x16_bf16(ar1, br0, acc[1][0], 0, 0, 0);
            acc[1][1] = __builtin_amdgcn_mfma_f32_32x32x16_bf16(ar1, br1, acc[1][1], 0, 0, 0);
        }
    }

    // Epilogue: bias, fold QSCALE into Q, scatter bf16 into [B,H,S,HD]
    const int bidx = m0 >> 11;
    const int which = n0 >> 11;           // block-uniform (n0 % 128 == 0)
    ushort* dst = (which == 0) ? Qo : ((which == 1) ? Ko : Vo);
    const float sc = (which == 0) ? QSCALE : 1.0f;
#pragma unroll
    for (int j = 0; j < 2; ++j) {
        int n = n0 + wc * 64 + j * 32 + l31;
        int c = n & 2047, h = c >> 7, hd = c & 127;
        float bv = bias[n];
        size_t base = ((size_t)(bidx * HH + h) * SS) * HDIM + hd;
#pragma unroll
        for (int i = 0; i < 2; ++i) {
#pragma unroll
            for (int r = 0; r < 16; ++r) {
                int s = (m0 & 2047) + wr * 64 + i * 32 + (r & 3) + 8 * (r >> 2) + 4 * hh;
                dst[base + (size_t)s * HDIM] = f2bf((acc[i][j][r] + bv) * sc);
            }
        }
    }
}

__global__ __launch_bounds__(256) void gemm_out_kernel(
    const ushort* __restrict__ A, const ushort* __restrict__ Bt,
    const float* __restrict__ bias, float* __restrict__ Out)
{
    const int n0 = blockIdx.x * 128;
    const int m0 = blockIdx.y * 128;
    __shared__ ushort As[128 * 64];
    __shared__ ushort Bs[128 * 64];
    const int t = threadIdx.x, w = t >> 6, lane = t & 63;
    const int l31 = lane & 31, hh = lane >> 5;
    const int wr = w >> 1, wc = w & 1;
    const int l7 = l31 & 7;

    const int rt   = lane >> 3;
    const int koff = ((lane & 7) ^ rt) * 8;

    f32x16 acc[2][2];
#pragma unroll
    for (int i = 0; i < 2; ++i)
#pragma unroll
        for (int j = 0; j < 2; ++j) acc[i][j] = (f32x16)0.f;

    for (int k0 = 0; k0 < DD; k0 += 64) {
        __syncthreads();
#pragma unroll
        for (int q = 0; q < 4; ++q) {
            int R = (w * 4 + q) * 8 + rt;
            gl16(A  + (size_t)(m0 + R) * DD + k0 + koff, &As[(w * 4 + q) * 512]);
            gl16(Bt + (size_t)(n0 + R) * DD + k0 + koff, &Bs[(w * 4 + q) * 512]);
        }
        __syncthreads();
#pragma unroll
        for (int k16 = 0; k16 < 4; ++k16) {
            int lg = (k16 >> 1) * 4 + (k16 & 1) * 2 + hh;
            int co = (lg ^ l7) * 8;
            bf16x8 ar0 = *(const bf16x8*)&As[(wr * 64 + l31) * 64 + co];
            bf16x8 ar1 = *(const bf16x8*)&As[(wr * 64 + 32 + l31) * 64 + co];
            bf16x8 br0 = *(const bf16x8*)&Bs[(wc * 64 + l31) * 64 + co];
            bf16x8 br1 = *(const bf16x8*)&Bs[(wc * 64 + 32 + l31) * 64 + co];
            acc[0][0] = __builtin_amdgcn_mfma_f32_32x32x16_bf16(ar0, br0, acc[0][0], 0, 0, 0);
            acc[0][1] = __builtin_amdgcn_mfma_f32_32x32x16_bf16(ar0, br1, acc[0][1], 0, 0, 0);
            acc[1][0] = __builtin_amdgcn_mfma_f32_32x32x16_bf16(ar1, br0, acc[1][0], 0, 0, 0);
            acc[1][1] = __builtin_amdgcn_mfma_f32_32x32x16_bf16(ar1, br1, acc[1][1], 0, 0, 0);
        }
    }

#pragma unroll
    for (int j = 0; j < 2; ++j) {
        int n = n0 + wc * 64 + j * 32 + l31;
        float bv = bias[n];
#pragma unroll
        for (int i = 0; i < 2; ++i) {
#pragma unroll
            for (int r = 0; r < 16; ++r) {
                int m = m0 + wr * 64 + i * 32 + (r & 3) + 8 * (r >> 2) + 4 * hh;
                Out[(size_t)m * DD + n] = acc[i][j][r] + bv;
            }
        }
    }
}

// ---------------------------------------------------------------------------
// MFMA flash attention: 32x32x16 MFMA, 128 q-rows/block, 4 waves.
// Swapped QK^T + in-register softmax; K/V double-buffered; load-balanced
// flat-512 block map (fid and fid+256 have qt summing to 15).
// LDS rows are 64 B (4 granules) -> reads already at the 4-way b128 floor.
// ---------------------------------------------------------------------------
__global__ __launch_bounds__(256, 2) void attn_mfma_kernel(
    const ushort* __restrict__ Q, const ushort* __restrict__ K,
    const ushort* __restrict__ Vt, ushort* __restrict__ Y)
{
    const int fid = blockIdx.x;
    const int halfg = fid >> 8, rg = fid & 255;
    const int qt = halfg ? (rg & 15) : (15 - (rg & 15));
    const int bh = (halfg << 4) | (rg >> 4);
    const int q0 = qt * 128;
    const int b = bh >> 4, h = bh & 15;

    __shared__ ushort Ks[2][4 * 64 * 32];   // [slot][panel ks: dims ks*32..+32, 64 keys]
    __shared__ ushort Vs[2][2 * 128 * 32];  // [slot][panel kp: keys kp*32..+32, 128 dims]

    const int t = threadIdx.x, w = t >> 6, lane = t & 63;
    const int l31 = lane & 31, hh = lane >> 5;
    const int lrow = lane >> 2, lks = lane & 3;
    const int swst = (lrow >> 1) & 3;    // store-side swizzle key
    const int swr  = (l31 >> 1) & 3;     // read-side swizzle key

    const ushort* Qp = Q  + (size_t)bh * SS * HDIM;
    const ushort* Kp = K  + (size_t)bh * SS * HDIM;
    const ushort* Vp = Vt + (size_t)bh * HDIM * SS;

    // Q fragments to registers: lane q-row = l31, k = kb2*16 + hh*8 + j
    bf16x8 aq[8];
#pragma unroll
    for (int kb2 = 0; kb2 < 8; ++kb2)
        aq[kb2] = *(const bf16x8*)(Qp + (size_t)(q0 + w * 32 + l31) * HDIM + kb2 * 16 + hh * 8);

    bf16x8 ones;
#pragma unroll
    for (int j = 0; j < 8; ++j) ones[j] = (short)0x3F80;  // bf16 1.0

    f32x16 O[4];
#pragma unroll
    for (int nt = 0; nt < 4; ++nt) O[nt] = (f32x16)0.f;
    f32x16 Ol = (f32x16)0.f;

    const int kbdiag = 2 * qt + (w >> 1);
    const int nkb = 2 * qt + 2;
    const bool hi = (hh == 1);
    const int qg = q0 + w * 32 + l31;    // this lane's q-row (S^T column)

    // stage K panel w (dims w*32..+32, 64 keys) + V dims w*32..+32 (both
    // 32-key panels) of tile kb_ into LDS slot s_, swizzled chunks
#define STAGE_KV(kb_, s_) do {                                                  \
    const int kbase_ = (kb_) * 64;                                              \
    _Pragma("unroll")                                                           \
    for (int g = 0; g < 4; ++g) {                                               \
        int key = g * 16 + lrow;                                                \
        gl16(Kp + (size_t)(kbase_ + key) * HDIM + w * 32 + (lks ^ swst) * 8,    \
             &Ks[s_][w * 2048 + g * 512]);                                      \
    }                                                                           \
    _Pragma("unroll")                                                           \
    for (int g = 0; g < 4; ++g) {                                               \
        int pan = g >> 1, sub = g & 1;                                          \
        int dim = w * 32 + sub * 16 + lrow;                                     \
        gl16(Vp + (size_t)dim * SS + kbase_ + pan * 32 + (lks ^ swst) * 8,      \
             &Vs[s_][pan * 4096 + (w * 32 + sub * 16) * 32]);                   \
    }                                                                           \
} while (0)

    STAGE_KV(0, 0);

    for (int kb = 0; kb < nkb; ++kb) {
        const int kbase = kb * 64;
        const int slot = kb & 1;

        if (kb + 1 < nkb) {
            STAGE_KV(kb + 1, slot ^ 1);
            asm volatile("s_waitcnt vmcnt(8)" ::: "memory");  // tile kb landed
        } else {
            asm volatile("s_waitcnt vmcnt(0)" ::: "memory");
        }
        __builtin_amdgcn_s_barrier();   // slot (kb&1) valid workgroup-wide

        const ushort* KsS = Ks[slot];
        const ushort* VsS = Vs[slot];

        if (kb <= kbdiag) {
            // S^T = K Q^T, two 32-key m-tiles (swapped operands: A=K, B=Q)
            f32x16 st0 = (f32x16)0.f, st1 = (f32x16)0.f;
            __builtin_amdgcn_s_setprio(1);
#pragma unroll
            for (int kb2 = 0; kb2 < 8; ++kb2) {
                int co = (((kb2 & 1) * 2 + hh) ^ swr) * 8;
                bf16x8 bk0 = *(const bf16x8*)&KsS[(kb2 >> 1) * 2048 + l31 * 32 + co];
                bf16x8 bk1 = *(const bf16x8*)&KsS[(kb2 >> 1) * 2048 + (32 + l31) * 32 + co];
                st0 = __builtin_amdgcn_mfma_f32_32x32x16_bf16(bk0, aq[kb2], st0, 0, 0, 0);
                st1 = __builtin_amdgcn_mfma_f32_32x32x16_bf16(bk1, aq[kb2], st1, 0, 0, 0);
            }
            __builtin_amdgcn_s_setprio(0);

            if (kb == kbdiag) {   // diagonal: causal mask (key > q-row)
#pragma unroll
                for (int r = 0; r < 16; ++r) {
                    int keyr = kbase + (r & 3) + 8 * (r >> 2) + 4 * hh;
                    if (keyr > qg)      st0[r] = -1e30f;
                    if (keyr + 32 > qg) st1[r] = -1e30f;
                }
            }

            // per 32-key half: exp2 -> pack bf16 pairs (plain C++) ->
            // shfl_xor(32) cross-half exchange -> PV A-frags
#pragma unroll
            for (int half = 0; half < 2; ++half) {
                float p[16];
#pragma unroll
                for (int r = 0; r < 16; ++r)
                    p[r] = __builtin_amdgcn_exp2f((half == 0) ? st0[r] : st1[r]);
                // word wX[g]: keys 8g+4hh + {2X, 2X+1}; low ushort = lower key
                uint w0[4], w1[4];
#pragma unroll
                for (int g = 0; g < 4; ++g) {
                    w0[g] = (uint)f2bf_fast(p[4 * g])
                          | ((uint)f2bf_fast(p[4 * g + 1]) << 16);
                    w1[g] = (uint)f2bf_fast(p[4 * g + 2])
                          | ((uint)f2bf_fast(p[4 * g + 3]) << 16);
                }
#pragma unroll
                for (int kblk2 = 0; kblk2 < 2; ++kblk2) {
                    // own group = 2*kblk2+hh ; send group = 2*kblk2+1-hh
                    uint own0 = hi ? w0[2 * kblk2 + 1] : w0[2 * kblk2];
                    uint own1 = hi ? w1[2 * kblk2 + 1] : w1[2 * kblk2];
                    uint snd0 = hi ? w0[2 * kblk2]     : w0[2 * kblk2 + 1];
                    uint snd1 = hi ? w1[2 * kblk2]     : w1[2 * kblk2 + 1];
                    uint ps0 = (uint)__shfl_xor((int)snd0, 32, 64);
                    uint ps1 = (uint)__shfl_xor((int)snd1, 32, 64);
                    union { uint u[4]; bf16x8 v; } fr;
                    fr.u[0] = hi ? ps0 : own0;   // keys kblk2*16+hh*8 + {0,1}
                    fr.u[1] = hi ? ps1 : own1;   // + {2,3}
                    fr.u[2] = hi ? own0 : ps0;   // + {4,5}
                    fr.u[3] = hi ? own1 : ps1;   // + {6,7}
                    int co = ((kblk2 * 2 + hh) ^ swr) * 8;
                    __builtin_amdgcn_s_setprio(1);
#pragma unroll
                    for (int nt = 0; nt < 4; ++nt) {
                        bf16x8 bv = *(const bf16x8*)&VsS[half * 4096 + (nt * 32 + l31) * 32 + co];
                        O[nt] = __builtin_amdgcn_mfma_f32_32x32x16_bf16(fr.v, bv, O[nt], 0, 0, 0);
                    }
                    Ol = __builtin_amdgcn_mfma_f32_32x32x16_bf16(fr.v, ones, Ol, 0, 0, 0);
                    __builtin_amdgcn_s_setprio(0);
                }
            }
        }
        __builtin_amdgcn_s_barrier();   // WAR guard before slot reuse
    }
#undef STAGE_KV

    // epilogue: divide by l, write Y[b,s,h*128+hd]
#pragma unroll
    for (int r = 0; r < 16; ++r) {
        int s = q0 + w * 32 + (r & 3) + 8 * (r >> 2) + 4 * hh;
        float inv = 1.0f / Ol[r];
        size_t base = ((size_t)(b * SS + s)) * DD + h * HDIM;
#pragma unroll
        for (int nt = 0; nt < 4; ++nt)
            Y[base + nt * 32 + l31] = f2bf(O[nt][r] * inv);
    }
}

// ---------------------------------------------------------------------------
extern "C" void kernel_launch(void* const* d_in, const int* in_sizes, int n_in,
                              void* d_out, int out_size, void* d_ws, size_t ws_size,
                              hipStream_t stream) {
    const float* x     = (const float*)d_in[0];
    const float* w_qkv = (const float*)d_in[1];
    const float* b_qkv = (const float*)d_in[2];
    const float* w_out = (const float*)d_in[3];
    const float* b_out = (const float*)d_in[4];
    float* out = (float*)d_out;

    ushort* ws  = (ushort*)d_ws;
    ushort* xb  = ws;                      // 8,388,608
    ushort* wtq = xb + 8388608;            // 12,582,912
    ushort* wto = wtq + 12582912;          // 4,194,304
    ushort* q   = wto + 4194304;           // 8,388,608
    ushort* k   = q + 8388608;
    ushort* v   = k + 8388608;             // [B,H,S,HD]
    ushort* vt  = v + 8388608;             // [B,H,HD,S]
    ushort* y   = vt + 8388608;

    cast_x_kernel<<<4096, 256, 0, stream>>>(x, xb);
    transpose_cast_kernel<<<dim3(192, 64), 256, 0, stream>>>(w_qkv, wtq, DD, 3 * DD);
    transpose_cast_kernel<<<dim3(64, 64), 256, 0, stream>>>(w_out, wto, DD, DD);
    gemm_qkv_kernel<<<dim3(48, 32), 256, 0, stream>>>(xb, wtq, b_qkv, q, k, v);
    transpose_v_kernel<<<dim3(64, 4, 32), 256, 0, stream>>>(v, vt);
    attn_mfma_kernel<<<dim3(512), 256, 0, stream>>>(q, k, vt, y);
    gemm_out_kernel<<<dim3(16, 32), 256, 0, stream>>>(y, wto, b_out, out);
}

// Round 9
// 368.336 us; speedup vs baseline: 1.1033x; 1.0132x over previous
//
#include <hip/hip_runtime.h>
#include <hip/hip_bf16.h>
#include <cstdint>
#include <cstddef>

#define BB 2
#define SS 2048
#define DD 2048
#define HH 16
#define HDIM 128
// 1/sqrt(128) * log2(e): folded into Q so softmax uses exp2 directly
#define QSCALE 0.12751743f

typedef short bf16x8 __attribute__((ext_vector_type(8)));
typedef float f32x4 __attribute__((ext_vector_type(4)));
typedef float f32x16 __attribute__((ext_vector_type(16)));

__device__ __forceinline__ ushort f2bf(float f) {
    union { float f; uint32_t u; } v; v.f = f;
    uint32_t u = v.u;
    u += 0x7fffu + ((u >> 16) & 1u);
    return (ushort)(u >> 16);
}

// cheap round-half-up f32->bf16 (2 VALU ops); fine for nonnegative p
__device__ __forceinline__ ushort f2bf_fast(float f) {
    union { float f; uint32_t u; } v; v.f = f;
    return (ushort)((v.u + 0x8000u) >> 16);
}

// async 16B global -> LDS (wave-uniform LDS base + lane*16)
__device__ __forceinline__ void gl16(const ushort* g, ushort* l) {
    __builtin_amdgcn_global_load_lds(
        (const __attribute__((address_space(1))) unsigned int*)g,
        (__attribute__((address_space(3))) unsigned int*)l,
        16, 0, 0);
}

// ---------------------------------------------------------------------------
// Prep kernels
// ---------------------------------------------------------------------------
__global__ __launch_bounds__(256) void cast_x_kernel(
    const float* __restrict__ X, ushort* __restrict__ Xb)
{
    size_t idx = ((size_t)blockIdx.x * 256 + threadIdx.x) * 8;
    float4 a = *(const float4*)(X + idx);
    float4 b = *(const float4*)(X + idx + 4);
    ushort4 o0, o1;
    o0.x = f2bf(a.x); o0.y = f2bf(a.y); o0.z = f2bf(a.z); o0.w = f2bf(a.w);
    o1.x = f2bf(b.x); o1.y = f2bf(b.y); o1.z = f2bf(b.z); o1.w = f2bf(b.w);
    *(ushort4*)(Xb + idx) = o0;
    *(ushort4*)(Xb + idx + 4) = o1;
}

// W fp32 [K][N] row-major -> Wt bf16 [N][K]
__global__ __launch_bounds__(256) void transpose_cast_kernel(
    const float* __restrict__ W, ushort* __restrict__ Wt, int K, int N)
{
    __shared__ ushort tile[32][36];
    const int n0 = blockIdx.x * 32;
    const int k0 = blockIdx.y * 32;
    const int t = threadIdx.x;
    const int r = t >> 3;
    const int c = (t & 7) * 4;
    float4 a = *(const float4*)(W + (size_t)(k0 + r) * N + n0 + c);
    tile[r][c + 0] = f2bf(a.x); tile[r][c + 1] = f2bf(a.y);
    tile[r][c + 2] = f2bf(a.z); tile[r][c + 3] = f2bf(a.w);
    __syncthreads();
    ushort4 o;
    o.x = tile[c + 0][r]; o.y = tile[c + 1][r];
    o.z = tile[c + 2][r]; o.w = tile[c + 3][r];
    *(ushort4*)(Wt + (size_t)(n0 + r) * K + k0 + c) = o;
}

// ---------------------------------------------------------------------------
// MFMA GEMM: C[M,N] = A[M,K] @ Bt[N,K]^T, 128x128 tile, BK=64, 3-bit granule
// swizzle (note: SQ_LDS_BANK_CONFLICT ~1.26e7 is the b128 column-read FLOOR
// for this pattern -- ~4 cy/read booked by the counter regardless of swizzle;
// verified constant across three layouts, r0/r6/r8).
// V output is written DIRECTLY TRANSPOSED ([bh][hd][s]) so transpose_v is
// deleted from the pipeline.
// ---------------------------------------------------------------------------
__global__ __launch_bounds__(256) void gemm_qkv_kernel(
    const ushort* __restrict__ A, const ushort* __restrict__ Bt,
    const float* __restrict__ bias,
    ushort* __restrict__ Qo, ushort* __restrict__ Ko, ushort* __restrict__ Vo)
{
    const int n0 = blockIdx.x * 128;
    const int m0 = blockIdx.y * 128;
    __shared__ ushort As[128 * 64];
    __shared__ ushort Bs[128 * 64];
    const int t = threadIdx.x, w = t >> 6, lane = t & 63;
    const int l31 = lane & 31, hh = lane >> 5;
    const int wr = w >> 1, wc = w & 1;
    const int l7 = l31 & 7;               // read-row mod 8 (all frag rows ≡ l31 mod 8)

    const int rt   = lane >> 3;
    const int koff = ((lane & 7) ^ rt) * 8;   // ushorts

    f32x16 acc[2][2];
#pragma unroll
    for (int i = 0; i < 2; ++i)
#pragma unroll
        for (int j = 0; j < 2; ++j) acc[i][j] = (f32x16)0.f;

    for (int k0 = 0; k0 < DD; k0 += 64) {
        __syncthreads();
#pragma unroll
        for (int q = 0; q < 4; ++q) {
            int R = (w * 4 + q) * 8 + rt;
            gl16(A  + (size_t)(m0 + R) * DD + k0 + koff, &As[(w * 4 + q) * 512]);
            gl16(Bt + (size_t)(n0 + R) * DD + k0 + koff, &Bs[(w * 4 + q) * 512]);
        }
        __syncthreads();
#pragma unroll
        for (int k16 = 0; k16 < 4; ++k16) {
            int lg = (k16 >> 1) * 4 + (k16 & 1) * 2 + hh;
            int co = (lg ^ l7) * 8;
            bf16x8 ar0 = *(const bf16x8*)&As[(wr * 64 + l31) * 64 + co];
            bf16x8 ar1 = *(const bf16x8*)&As[(wr * 64 + 32 + l31) * 64 + co];
            bf16x8 br0 = *(const bf16x8*)&Bs[(wc * 64 + l31) * 64 + co];
            bf16x8 br1 = *(const bf16x8*)&Bs[(wc * 64 + 32 + l31) * 64 + co];
            acc[0][0] = __builtin_amdgcn_mfma_f32_32x32x16_bf16(ar0, br0, acc[0][0], 0, 0, 0);
            acc[0][1] = __builtin_amdgcn_mfma_f32_32x32x16_bf16(ar0, br1, acc[0][1], 0, 0, 0);
            acc[1][0] = __builtin_amdgcn_mfma_f32_32x32x16_bf16(ar1, br0, acc[1][0], 0, 0, 0);
            acc[1][1] = __builtin_amdgcn_mfma_f32_32x32x16_bf16(ar1, br1, acc[1][1], 0, 0, 0);
        }
    }

    // Epilogue: bias; Q scaled by QSCALE; V written transposed [bh][hd][s]
    const int bidx = m0 >> 11;
    const int which = n0 >> 11;           // block-uniform (n0 % 128 == 0)
    if (which == 2) {
#pragma unroll
        for (int j = 0; j < 2; ++j) {
            int n = n0 + wc * 64 + j * 32 + l31;
            int c = n & 2047, h = c >> 7, hd = c & 127;
            float bv = bias[n];
            // s = (m0&2047) + wr*64 + i*32 + 8g + 4hh + q  (q=0..3 contiguous)
            size_t vbase = ((size_t)(bidx * HH + h) * HDIM + hd) * SS
                         + (m0 & 2047) + wr * 64 + 4 * hh;
#pragma unroll
            for (int i = 0; i < 2; ++i) {
#pragma unroll
                for (int g = 0; g < 4; ++g) {
                    ushort4 o;
                    o.x = f2bf(acc[i][j][4 * g + 0] + bv);
                    o.y = f2bf(acc[i][j][4 * g + 1] + bv);
                    o.z = f2bf(acc[i][j][4 * g + 2] + bv);
                    o.w = f2bf(acc[i][j][4 * g + 3] + bv);
                    *(ushort4*)&Vo[vbase + i * 32 + 8 * g] = o;
                }
            }
        }
    } else {
        ushort* dst = (which == 0) ? Qo : Ko;
        const float sc = (which == 0) ? QSCALE : 1.0f;
#pragma unroll
        for (int j = 0; j < 2; ++j) {
            int n = n0 + wc * 64 + j * 32 + l31;
            int c = n & 2047, h = c >> 7, hd = c & 127;
            float bv = bias[n];
            size_t base = ((size_t)(bidx * HH + h) * SS) * HDIM + hd;
#pragma unroll
            for (int i = 0; i < 2; ++i) {
#pragma unroll
                for (int r = 0; r < 16; ++r) {
                    int s = (m0 & 2047) + wr * 64 + i * 32 + (r & 3) + 8 * (r >> 2) + 4 * hh;
                    dst[base + (size_t)s * HDIM] = f2bf((acc[i][j][r] + bv) * sc);
                }
            }
        }
    }
}

__global__ __launch_bounds__(256) void gemm_out_kernel(
    const ushort* __restrict__ A, const ushort* __restrict__ Bt,
    const float* __restrict__ bias, float* __restrict__ Out)
{
    const int n0 = blockIdx.x * 128;
    const int m0 = blockIdx.y * 128;
    __shared__ ushort As[128 * 64];
    __shared__ ushort Bs[128 * 64];
    const int t = threadIdx.x, w = t >> 6, lane = t & 63;
    const int l31 = lane & 31, hh = lane >> 5;
    const int wr = w >> 1, wc = w & 1;
    const int l7 = l31 & 7;

    const int rt   = lane >> 3;
    const int koff = ((lane & 7) ^ rt) * 8;

    f32x16 acc[2][2];
#pragma unroll
    for (int i = 0; i < 2; ++i)
#pragma unroll
        for (int j = 0; j < 2; ++j) acc[i][j] = (f32x16)0.f;

    for (int k0 = 0; k0 < DD; k0 += 64) {
        __syncthreads();
#pragma unroll
        for (int q = 0; q < 4; ++q) {
            int R = (w * 4 + q) * 8 + rt;
            gl16(A  + (size_t)(m0 + R) * DD + k0 + koff, &As[(w * 4 + q) * 512]);
            gl16(Bt + (size_t)(n0 + R) * DD + k0 + koff, &Bs[(w * 4 + q) * 512]);
        }
        __syncthreads();
#pragma unroll
        for (int k16 = 0; k16 < 4; ++k16) {
            int lg = (k16 >> 1) * 4 + (k16 & 1) * 2 + hh;
            int co = (lg ^ l7) * 8;
            bf16x8 ar0 = *(const bf16x8*)&As[(wr * 64 + l31) * 64 + co];
            bf16x8 ar1 = *(const bf16x8*)&As[(wr * 64 + 32 + l31) * 64 + co];
            bf16x8 br0 = *(const bf16x8*)&Bs[(wc * 64 + l31) * 64 + co];
            bf16x8 br1 = *(const bf16x8*)&Bs[(wc * 64 + 32 + l31) * 64 + co];
            acc[0][0] = __builtin_amdgcn_mfma_f32_32x32x16_bf16(ar0, br0, acc[0][0], 0, 0, 0);
            acc[0][1] = __builtin_amdgcn_mfma_f32_32x32x16_bf16(ar0, br1, acc[0][1], 0, 0, 0);
            acc[1][0] = __builtin_amdgcn_mfma_f32_32x32x16_bf16(ar1, br0, acc[1][0], 0, 0, 0);
            acc[1][1] = __builtin_amdgcn_mfma_f32_32x32x16_bf16(ar1, br1, acc[1][1], 0, 0, 0);
        }
    }

#pragma unroll
    for (int j = 0; j < 2; ++j) {
        int n = n0 + wc * 64 + j * 32 + l31;
        float bv = bias[n];
#pragma unroll
        for (int i = 0; i < 2; ++i) {
#pragma unroll
            for (int r = 0; r < 16; ++r) {
                int m = m0 + wr * 64 + i * 32 + (r & 3) + 8 * (r >> 2) + 4 * hh;
                Out[(size_t)m * DD + n] = acc[i][j][r] + bv;
            }
        }
    }
}

// ---------------------------------------------------------------------------
// MFMA flash attention: 32x32x16 MFMA, 128 q-rows/block, 4 waves.
// Swapped QK^T + in-register softmax; K/V double-buffered.
//
// Round-9 change: XCD-CLUSTERED block map. Attn is cache-bound: 557 MB of
// K/V re-streaming vs a 4 us MFMA floor. Old map spread each bh's 16
// q-blocks across all XCDs -> every 4 MB L2 thrashed over the full 32 MB
// K/V working set (L3-served). New map: xcd = fid&7 (HW round-robins
// consecutive ids across XCDs), bh = (j>>4)*8 + xcd -> each XCD serves only
// 4 bh = 4 MB of K/V, L2-resident. Balance: CU pairs (j, j+32) have qt
// summing to 15 -> 34 tile-iters per CU; heavy blocks dispatch first.
// ---------------------------------------------------------------------------
__global__ __launch_bounds__(256, 2) void attn_mfma_kernel(
    const ushort* __restrict__ Q, const ushort* __restrict__ K,
    const ushort* __restrict__ Vt, ushort* __restrict__ Y)
{
    const int fid = blockIdx.x;
    const int xcd = fid & 7;
    const int j   = fid >> 3;            // 0..63 within XCD
    const int bhsub = j >> 4;            // 4 bh per XCD
    const int bh  = bhsub * 8 + xcd;
    const int jr  = j & 15;
    const int qt  = (bhsub & 2) ? jr : (15 - jr);   // pairs sum to 15; heavy early
    const int q0 = qt * 128;
    const int b = bh >> 4, h = bh & 15;

    __shared__ ushort Ks[2][4 * 64 * 32];   // [slot][panel ks: dims ks*32..+32, 64 keys]
    __shared__ ushort Vs[2][2 * 128 * 32];  // [slot][panel kp: keys kp*32..+32, 128 dims]

    const int t = threadIdx.x, w = t >> 6, lane = t & 63;
    const int l31 = lane & 31, hh = lane >> 5;
    const int lrow = lane >> 2, lks = lane & 3;
    const int swst = (lrow >> 1) & 3;    // store-side swizzle key
    const int swr  = (l31 >> 1) & 3;     // read-side swizzle key

    const ushort* Qp = Q  + (size_t)bh * SS * HDIM;
    const ushort* Kp = K  + (size_t)bh * SS * HDIM;
    const ushort* Vp = Vt + (size_t)bh * HDIM * SS;

    // Q fragments to registers: lane q-row = l31, k = kb2*16 + hh*8 + j
    bf16x8 aq[8];
#pragma unroll
    for (int kb2 = 0; kb2 < 8; ++kb2)
        aq[kb2] = *(const bf16x8*)(Qp + (size_t)(q0 + w * 32 + l31) * HDIM + kb2 * 16 + hh * 8);

    bf16x8 ones;
#pragma unroll
    for (int jj = 0; jj < 8; ++jj) ones[jj] = (short)0x3F80;  // bf16 1.0

    f32x16 O[4];
#pragma unroll
    for (int nt = 0; nt < 4; ++nt) O[nt] = (f32x16)0.f;
    f32x16 Ol = (f32x16)0.f;

    const int kbdiag = 2 * qt + (w >> 1);
    const int nkb = 2 * qt + 2;
    const bool hi = (hh == 1);
    const int qg = q0 + w * 32 + l31;    // this lane's q-row (S^T column)

    // stage K panel w (dims w*32..+32, 64 keys) + V dims w*32..+32 (both
    // 32-key panels) of tile kb_ into LDS slot s_, swizzled chunks
#define STAGE_KV(kb_, s_) do {                                                  \
    const int kbase_ = (kb_) * 64;                                              \
    _Pragma("unroll")                                                           \
    for (int g = 0; g < 4; ++g) {                                               \
        int key = g * 16 + lrow;                                                \
        gl16(Kp + (size_t)(kbase_ + key) * HDIM + w * 32 + (lks ^ swst) * 8,    \
             &Ks[s_][w * 2048 + g * 512]);                                      \
    }                                                                           \
    _Pragma("unroll")                                                           \
    for (int g = 0; g < 4; ++g) {                                               \
        int pan = g >> 1, sub = g & 1;                                          \
        int dim = w * 32 + sub * 16 + lrow;                                     \
        gl16(Vp + (size_t)dim * SS + kbase_ + pan * 32 + (lks ^ swst) * 8,      \
             &Vs[s_][pan * 4096 + (w * 32 + sub * 16) * 32]);                   \
    }                                                                           \
} while (0)

    STAGE_KV(0, 0);

    for (int kb = 0; kb < nkb; ++kb) {
        const int kbase = kb * 64;
        const int slot = kb & 1;

        if (kb + 1 < nkb) {
            STAGE_KV(kb + 1, slot ^ 1);
            asm volatile("s_waitcnt vmcnt(8)" ::: "memory");  // tile kb landed
        } else {
            asm volatile("s_waitcnt vmcnt(0)" ::: "memory");
        }
        __builtin_amdgcn_s_barrier();   // slot (kb&1) valid workgroup-wide

        const ushort* KsS = Ks[slot];
        const ushort* VsS = Vs[slot];

        if (kb <= kbdiag) {
            // S^T = K Q^T, two 32-key m-tiles (swapped operands: A=K, B=Q)
            f32x16 st0 = (f32x16)0.f, st1 = (f32x16)0.f;
            __builtin_amdgcn_s_setprio(1);
#pragma unroll
            for (int kb2 = 0; kb2 < 8; ++kb2) {
                int co = (((kb2 & 1) * 2 + hh) ^ swr) * 8;
                bf16x8 bk0 = *(const bf16x8*)&KsS[(kb2 >> 1) * 2048 + l31 * 32 + co];
                bf16x8 bk1 = *(const bf16x8*)&KsS[(kb2 >> 1) * 2048 + (32 + l31) * 32 + co];
                st0 = __builtin_amdgcn_mfma_f32_32x32x16_bf16(bk0, aq[kb2], st0, 0, 0, 0);
                st1 = __builtin_amdgcn_mfma_f32_32x32x16_bf16(bk1, aq[kb2], st1, 0, 0, 0);
            }
            __builtin_amdgcn_s_setprio(0);

            if (kb == kbdiag) {   // diagonal: causal mask (key > q-row)
#pragma unroll
                for (int r = 0; r < 16; ++r) {
                    int keyr = kbase + (r & 3) + 8 * (r >> 2) + 4 * hh;
                    if (keyr > qg)      st0[r] = -1e30f;
                    if (keyr + 32 > qg) st1[r] = -1e30f;
                }
            }

            // per 32-key half: exp2 -> pack bf16 pairs (plain C++) ->
            // shfl_xor(32) cross-half exchange -> PV A-frags
#pragma unroll
            for (int half = 0; half < 2; ++half) {
                float p[16];
#pragma unroll
                for (int r = 0; r < 16; ++r)
                    p[r] = __builtin_amdgcn_exp2f((half == 0) ? st0[r] : st1[r]);
                // word wX[g]: keys 8g+4hh + {2X, 2X+1}; low ushort = lower key
                uint w0[4], w1[4];
#pragma unroll
                for (int g = 0; g < 4; ++g) {
                    w0[g] = (uint)f2bf_fast(p[4 * g])
                          | ((uint)f2bf_fast(p[4 * g + 1]) << 16);
                    w1[g] = (uint)f2bf_fast(p[4 * g + 2])
                          | ((uint)f2bf_fast(p[4 * g + 3]) << 16);
                }
#pragma unroll
                for (int kblk2 = 0; kblk2 < 2; ++kblk2) {
                    // own group = 2*kblk2+hh ; send group = 2*kblk2+1-hh
                    uint own0 = hi ? w0[2 * kblk2 + 1] : w0[2 * kblk2];
                    uint own1 = hi ? w1[2 * kblk2 + 1] : w1[2 * kblk2];
                    uint snd0 = hi ? w0[2 * kblk2]     : w0[2 * kblk2 + 1];
                    uint snd1 = hi ? w1[2 * kblk2]     : w1[2 * kblk2 + 1];
                    uint ps0 = (uint)__shfl_xor((int)snd0, 32, 64);
                    uint ps1 = (uint)__shfl_xor((int)snd1, 32, 64);
                    union { uint u[4]; bf16x8 v; } fr;
                    fr.u[0] = hi ? ps0 : own0;   // keys kblk2*16+hh*8 + {0,1}
                    fr.u[1] = hi ? ps1 : own1;   // + {2,3}
                    fr.u[2] = hi ? own0 : ps0;   // + {4,5}
                    fr.u[3] = hi ? own1 : ps1;   // + {6,7}
                    int co = ((kblk2 * 2 + hh) ^ swr) * 8;
                    __builtin_amdgcn_s_setprio(1);
#pragma unroll
                    for (int nt = 0; nt < 4; ++nt) {
                        bf16x8 bv = *(const bf16x8*)&VsS[half * 4096 + (nt * 32 + l31) * 32 + co];
                        O[nt] = __builtin_amdgcn_mfma_f32_32x32x16_bf16(fr.v, bv, O[nt], 0, 0, 0);
                    }
                    Ol = __builtin_amdgcn_mfma_f32_32x32x16_bf16(fr.v, ones, Ol, 0, 0, 0);
                    __builtin_amdgcn_s_setprio(0);
                }
            }
        }
        __builtin_amdgcn_s_barrier();   // WAR guard before slot reuse
    }
#undef STAGE_KV

    // epilogue: divide by l, write Y[b,s,h*128+hd]
#pragma unroll
    for (int r = 0; r < 16; ++r) {
        int s = q0 + w * 32 + (r & 3) + 8 * (r >> 2) + 4 * hh;
        float inv = 1.0f / Ol[r];
        size_t base = ((size_t)(b * SS + s)) * DD + h * HDIM;
#pragma unroll
        for (int nt = 0; nt < 4; ++nt)
            Y[base + nt * 32 + l31] = f2bf(O[nt][r] * inv);
    }
}

// ---------------------------------------------------------------------------
extern "C" void kernel_launch(void* const* d_in, const int* in_sizes, int n_in,
                              void* d_out, int out_size, void* d_ws, size_t ws_size,
                              hipStream_t stream) {
    const float* x     = (const float*)d_in[0];
    const float* w_qkv = (const float*)d_in[1];
    const float* b_qkv = (const float*)d_in[2];
    const float* w_out = (const float*)d_in[3];
    const float* b_out = (const float*)d_in[4];
    float* out = (float*)d_out;

    ushort* ws  = (ushort*)d_ws;
    ushort* xb  = ws;                      // 8,388,608
    ushort* wtq = xb + 8388608;            // 12,582,912
    ushort* wto = wtq + 12582912;          // 4,194,304
    ushort* q   = wto + 4194304;           // 8,388,608
    ushort* k   = q + 8388608;
    ushort* v   = k + 8388608;             // (unused; kept for layout stability)
    ushort* vt  = v + 8388608;             // [B,H,HD,S] -- written directly by gemm_qkv
    ushort* y   = vt + 8388608;

    cast_x_kernel<<<4096, 256, 0, stream>>>(x, xb);
    transpose_cast_kernel<<<dim3(192, 64), 256, 0, stream>>>(w_qkv, wtq, DD, 3 * DD);
    transpose_cast_kernel<<<dim3(64, 64), 256, 0, stream>>>(w_out, wto, DD, DD);
    gemm_qkv_kernel<<<dim3(48, 32), 256, 0, stream>>>(xb, wtq, b_qkv, q, k, vt);
    attn_mfma_kernel<<<dim3(512), 256, 0, stream>>>(q, k, vt, y);
    gemm_out_kernel<<<dim3(16, 32), 256, 0, stream>>>(y, wto, b_out, out);
}